// Round 1
// baseline (1066.135 us; speedup 1.0000x reference)
//
#include <hip/hip_runtime.h>
#include <hip/hip_bf16.h>
#include <stdint.h>

#define F 256            // IN_F == OUT_F == 256
#define KSTEP 32

typedef short bhalf8 __attribute__((ext_vector_type(8)));
typedef float f32x4 __attribute__((ext_vector_type(4)));

__device__ __forceinline__ unsigned short f2b(float f) {
    union { float f; uint32_t u; } x; x.f = f;
    uint32_t u = x.u;
    return (unsigned short)((u + 0x7FFFu + ((u >> 16) & 1u)) >> 16);
}
__device__ __forceinline__ float b2f(unsigned short h) {
    union { uint32_t u; float f; } x; x.u = ((uint32_t)h) << 16;
    return x.f;
}

// ---------------------------------------------------------------------------
// Dense: mT = elu(mean@Wm + bm) * exp(-relu(var@Wv + bv))
//        vT = relu(var@Wv + bv) * exp(-relu(...))^2        (both stored bf16)
// Block: 64 rows x 256 cols, 512 threads (8 waves, 2x4 wave grid).
// ---------------------------------------------------------------------------
__global__ __launch_bounds__(512) void dense_kernel(
    const float* __restrict__ mean, const float* __restrict__ var,
    const float* __restrict__ Wm, const float* __restrict__ bm,
    const float* __restrict__ Wv, const float* __restrict__ bv,
    unsigned short* __restrict__ mT, unsigned short* __restrict__ vT, int N)
{
    __shared__ unsigned short Asm[64][40];   // A tiles, +8 pad (bank spread)
    __shared__ unsigned short Asv[64][40];
    __shared__ unsigned short Bsm[256][40];  // W^T tiles: Bs[n][k]
    __shared__ unsigned short Bsv[256][40];

    const int tid  = threadIdx.x;
    const int row0 = blockIdx.x * 64;
    const int lane = tid & 63;
    const int w    = tid >> 6;
    const int wr   = w >> 2;          // 0..1 : 32-row half
    const int wc   = w & 3;           // 0..3 : 64-col slice
    const int lr   = lane & 15;
    const int lk   = lane >> 4;

    f32x4 accm[2][4], accv[2][4];
    #pragma unroll
    for (int i = 0; i < 2; ++i)
        #pragma unroll
        for (int j = 0; j < 4; ++j) { accm[i][j] = (f32x4)0.f; accv[i][j] = (f32x4)0.f; }

    // A-staging mapping: 512 threads cover 64 rows x 32 k (4 floats each)
    const int srow = tid >> 3;
    const int skq  = (tid & 7) * 4;
    int sgrow = row0 + srow; if (sgrow >= N) sgrow = N - 1;
    // W-staging mapping: 512 threads cover 32 k x 256 n (16 k's each)
    const int wn  = tid & 255;
    const int wkh = tid >> 8;     // 0..1

    for (int ks = 0; ks < F / KSTEP; ++ks) {
        const int k0 = ks * KSTEP;
        // stage A (f32 -> bf16)
        {
            const float4 am = *(const float4*)&mean[(size_t)sgrow * F + k0 + skq];
            const float4 av = *(const float4*)&var [(size_t)sgrow * F + k0 + skq];
            ushort4 um = { f2b(am.x), f2b(am.y), f2b(am.z), f2b(am.w) };
            ushort4 uv = { f2b(av.x), f2b(av.y), f2b(av.z), f2b(av.w) };
            *(ushort4*)&Asm[srow][skq] = um;
            *(ushort4*)&Asv[srow][skq] = uv;
        }
        // stage W^T (coalesced reads across n; bf16 rows of Bs[n][k])
        {
            unsigned short tm[16], tv[16];
            #pragma unroll
            for (int j = 0; j < 16; ++j) {
                int k = k0 + wkh * 16 + j;
                tm[j] = f2b(Wm[k * F + wn]);
                tv[j] = f2b(Wv[k * F + wn]);
            }
            #pragma unroll
            for (int q = 0; q < 4; ++q) {
                ushort4 pm = { tm[q*4+0], tm[q*4+1], tm[q*4+2], tm[q*4+3] };
                ushort4 pv = { tv[q*4+0], tv[q*4+1], tv[q*4+2], tv[q*4+3] };
                *(ushort4*)&Bsm[wn][wkh*16 + q*4] = pm;
                *(ushort4*)&Bsv[wn][wkh*16 + q*4] = pv;
            }
        }
        __syncthreads();

        bhalf8 am0 = *(const bhalf8*)&Asm[wr*32 +  0 + lr][lk*8];
        bhalf8 am1 = *(const bhalf8*)&Asm[wr*32 + 16 + lr][lk*8];
        bhalf8 av0 = *(const bhalf8*)&Asv[wr*32 +  0 + lr][lk*8];
        bhalf8 av1 = *(const bhalf8*)&Asv[wr*32 + 16 + lr][lk*8];
        #pragma unroll
        for (int ct = 0; ct < 4; ++ct) {
            bhalf8 bmf = *(const bhalf8*)&Bsm[wc*64 + ct*16 + lr][lk*8];
            bhalf8 bvf = *(const bhalf8*)&Bsv[wc*64 + ct*16 + lr][lk*8];
            accm[0][ct] = __builtin_amdgcn_mfma_f32_16x16x32_bf16(am0, bmf, accm[0][ct], 0, 0, 0);
            accm[1][ct] = __builtin_amdgcn_mfma_f32_16x16x32_bf16(am1, bmf, accm[1][ct], 0, 0, 0);
            accv[0][ct] = __builtin_amdgcn_mfma_f32_16x16x32_bf16(av0, bvf, accv[0][ct], 0, 0, 0);
            accv[1][ct] = __builtin_amdgcn_mfma_f32_16x16x32_bf16(av1, bvf, accv[1][ct], 0, 0, 0);
        }
        __syncthreads();
    }

    // epilogue: bias + elu/relu + attention, store bf16
    #pragma unroll
    for (int rt = 0; rt < 2; ++rt) {
        #pragma unroll
        for (int ct = 0; ct < 4; ++ct) {
            const int col = wc*64 + ct*16 + lr;
            const float bmc = bm[col], bvc = bv[col];
            #pragma unroll
            for (int q = 0; q < 4; ++q) {
                int grow = row0 + wr*32 + rt*16 + lk*4 + q;
                if (grow < N) {
                    float mp = accm[rt][ct][q] + bmc;
                    float vp = accv[rt][ct][q] + bvc;
                    float me = mp > 0.f ? mp : (__expf(mp) - 1.f);   // elu
                    float vr = vp > 0.f ? vp : 0.f;                  // relu
                    float att = __expf(-vr);
                    mT[(size_t)grow * F + col] = f2b(me * att);
                    vT[(size_t)grow * F + col] = f2b(vr * att * att);
                }
            }
        }
    }
}

// ---------------------------------------------------------------------------
// CSR build
// ---------------------------------------------------------------------------
__global__ void hist_kernel(const int* __restrict__ row, int E, int* __restrict__ count) {
    int i = blockIdx.x * blockDim.x + threadIdx.x;
    if (i < E) atomicAdd(&count[row[i]], 1);
}

__global__ __launch_bounds__(256) void scan1_kernel(const int* __restrict__ count, int N,
                                                    int* __restrict__ offs, int* __restrict__ bsums)
{
    __shared__ int sd[256];
    int t  = threadIdx.x;
    int gi = blockIdx.x * 1024 + t * 4;
    int c[4];
    #pragma unroll
    for (int q = 0; q < 4; ++q) c[q] = (gi + q < N) ? count[gi + q] : 0;
    int s = c[0] + c[1] + c[2] + c[3];
    sd[t] = s; __syncthreads();
    int acc = s;
    for (int off = 1; off < 256; off <<= 1) {
        int u = (t >= off) ? sd[t - off] : 0;
        __syncthreads();
        acc += u; sd[t] = acc;
        __syncthreads();
    }
    int run = acc - s;  // exclusive base for this thread
    #pragma unroll
    for (int q = 0; q < 4; ++q) { if (gi + q < N) offs[gi + q] = run; run += c[q]; }
    if (t == 255) bsums[blockIdx.x] = acc;
}

__global__ __launch_bounds__(128) void scan2_kernel(int* __restrict__ bsums, int SB,
                                                    int* __restrict__ offs, int N)
{
    __shared__ int sd[128];
    int t = threadIdx.x;
    int v = (t < SB) ? bsums[t] : 0;
    sd[t] = v; __syncthreads();
    int acc = v;
    for (int off = 1; off < 128; off <<= 1) {
        int u = (t >= off) ? sd[t - off] : 0;
        __syncthreads();
        acc += u; sd[t] = acc;
        __syncthreads();
    }
    if (t < SB) bsums[t] = acc - v;   // exclusive
    if (t == 127) offs[N] = sd[127];  // total == E
}

__global__ __launch_bounds__(256) void scan3_kernel(int* __restrict__ offs, int N,
                                                    const int* __restrict__ bsums)
{
    int b  = bsums[blockIdx.x];
    int gi = blockIdx.x * 1024 + threadIdx.x * 4;
    #pragma unroll
    for (int q = 0; q < 4; ++q) if (gi + q < N) offs[gi + q] += b;
}

__global__ void fill_kernel(const int* __restrict__ row, const int* __restrict__ col,
                            const float* __restrict__ a0, const float* __restrict__ a1,
                            int E, int* __restrict__ cursor,
                            int* __restrict__ ccol, float* __restrict__ cv0, float* __restrict__ cv1)
{
    int i = blockIdx.x * blockDim.x + threadIdx.x;
    if (i < E) {
        int r   = row[i];
        int pos = atomicAdd(&cursor[r], 1);
        ccol[pos] = col[i];
        cv0[pos]  = a0[i];
        cv1[pos]  = a1[i];
    }
}

// ---------------------------------------------------------------------------
// Fused SpMM (both adjacencies share structure): 1 wave per node.
// ---------------------------------------------------------------------------
__global__ __launch_bounds__(256) void spmm_kernel(
    const int* __restrict__ offs, const int* __restrict__ ccol,
    const float* __restrict__ cv0, const float* __restrict__ cv1,
    const unsigned short* __restrict__ mT, const unsigned short* __restrict__ vT,
    float* __restrict__ outm, float* __restrict__ outv, int N)
{
    int w    = threadIdx.x >> 6;
    int lane = threadIdx.x & 63;
    int node = blockIdx.x * 4 + w;
    if (node >= N) return;
    int s = offs[node], e = offs[node + 1];
    const int fb = lane * 4;
    float am0 = 0.f, am1 = 0.f, am2 = 0.f, am3 = 0.f;
    float av0 = 0.f, av1 = 0.f, av2 = 0.f, av3 = 0.f;
    for (int j = s; j < e; ++j) {
        int c    = ccol[j];
        float v0 = cv0[j];
        float v1 = cv1[j];
        ushort4 pm = *(const ushort4*)&mT[(size_t)c * F + fb];
        ushort4 pv = *(const ushort4*)&vT[(size_t)c * F + fb];
        am0 += v0 * b2f(pm.x); am1 += v0 * b2f(pm.y);
        am2 += v0 * b2f(pm.z); am3 += v0 * b2f(pm.w);
        av0 += v1 * b2f(pv.x); av1 += v1 * b2f(pv.y);
        av2 += v1 * b2f(pv.z); av3 += v1 * b2f(pv.w);
    }
    float4 om = { am0, am1, am2, am3 };
    float4 ov = { av0, av1, av2, av3 };
    *(float4*)&outm[(size_t)node * F + fb] = om;
    *(float4*)&outv[(size_t)node * F + fb] = ov;
}

// ---------------------------------------------------------------------------
extern "C" void kernel_launch(void* const* d_in, const int* in_sizes, int n_in,
                              void* d_out, int out_size, void* d_ws, size_t ws_size,
                              hipStream_t stream)
{
    const float* mean = (const float*)d_in[0];
    const float* var  = (const float*)d_in[1];
    const float* Wm   = (const float*)d_in[2];
    const float* bm   = (const float*)d_in[3];
    const float* Wv   = (const float*)d_in[4];
    const float* bv   = (const float*)d_in[5];
    const int*   erow = (const int*)d_in[6];
    const int*   ecol = (const int*)d_in[7];
    const float* a0   = (const float*)d_in[8];
    const float* a1   = (const float*)d_in[9];

    const int N = in_sizes[0] / F;     // 100000
    const int E = in_sizes[6];         // 3200000

    // workspace carve (256B aligned)
    uintptr_t p = (uintptr_t)d_ws;
    auto take = [&](size_t bytes) {
        uintptr_t r = (p + 255) & ~(uintptr_t)255;
        p = r + bytes;
        return (void*)r;
    };
    unsigned short* mT = (unsigned short*)take((size_t)N * F * 2);
    unsigned short* vT = (unsigned short*)take((size_t)N * F * 2);
    int*   ccol   = (int*)take((size_t)E * 4);
    float* cv0    = (float*)take((size_t)E * 4);
    float* cv1    = (float*)take((size_t)E * 4);
    int*   count  = (int*)take((size_t)N * 4);
    int*   offs   = (int*)take((size_t)(N + 1) * 4);
    int*   cursor = (int*)take((size_t)N * 4);
    int*   bsums  = (int*)take(1024 * 4);

    const int SB = (N + 1023) / 1024;  // 98 <= 128

    hipMemsetAsync(count, 0, (size_t)N * 4, stream);

    dense_kernel<<<(N + 63) / 64, 512, 0, stream>>>(mean, var, Wm, bm, Wv, bv, mT, vT, N);

    hist_kernel<<<(E + 255) / 256, 256, 0, stream>>>(erow, E, count);
    scan1_kernel<<<SB, 256, 0, stream>>>(count, N, offs, bsums);
    scan2_kernel<<<1, 128, 0, stream>>>(bsums, SB, offs, N);
    scan3_kernel<<<SB, 256, 0, stream>>>(offs, N, bsums);
    hipMemcpyAsync(cursor, offs, (size_t)N * 4, hipMemcpyDeviceToDevice, stream);
    fill_kernel<<<(E + 255) / 256, 256, 0, stream>>>(erow, ecol, a0, a1, E, cursor, ccol, cv0, cv1);

    float* outm = (float*)d_out;
    float* outv = outm + (size_t)N * F;
    spmm_kernel<<<(N + 3) / 4, 256, 0, stream>>>(offs, ccol, cv0, cv1, mT, vT, outm, outv, N);
}

// Round 2
// 892.631 us; speedup vs baseline: 1.1944x; 1.1944x over previous
//
#include <hip/hip_runtime.h>
#include <hip/hip_bf16.h>
#include <stdint.h>

#define F 256            // IN_F == OUT_F == 256
#define KSTEP 32

typedef short bhalf8 __attribute__((ext_vector_type(8)));
typedef unsigned short ushort8 __attribute__((ext_vector_type(8)));
typedef float f32x4 __attribute__((ext_vector_type(4)));

__device__ __forceinline__ unsigned short f2b(float f) {
    union { float f; uint32_t u; } x; x.f = f;
    uint32_t u = x.u;
    return (unsigned short)((u + 0x7FFFu + ((u >> 16) & 1u)) >> 16);
}
__device__ __forceinline__ float b2f(unsigned short h) {
    union { uint32_t u; float f; } x; x.u = ((uint32_t)h) << 16;
    return x.f;
}

// ---------------------------------------------------------------------------
// W prep: convert f32 W[k][n] -> bf16, pre-tiled per K-step in the exact LDS
// staging image: Wt[sel][ks][n][kk]  (sel: 0=mean 1=var, ks: K-step, kk 0..31)
// ---------------------------------------------------------------------------
__global__ __launch_bounds__(256) void wprep_kernel(
    const float* __restrict__ Wm, const float* __restrict__ Wv,
    unsigned short* __restrict__ Wt)
{
    int idx = blockIdx.x * 256 + threadIdx.x;   // 4096 = 2 sel * 8 ks * 256 n
    int sel = idx >> 11;
    int ks  = (idx >> 8) & 7;
    int n   = idx & 255;
    const float* W = sel ? Wv : Wm;
    unsigned short* dst = Wt + ((size_t)sel * 8 * 256 * 32) + ((size_t)(ks * 256 + n) * 32);
    #pragma unroll
    for (int kk = 0; kk < 32; ++kk)
        dst[kk] = f2b(W[(ks * 32 + kk) * 256 + n]);
}

// ---------------------------------------------------------------------------
// Dense: m' = elu(mean@Wm + bm) * att ;  v' = relu(var@Wv + bv) * att^2
// with att = exp(-relu(var@Wv+bv)). Stored bf16 INTERLEAVED: mv[row][512]
// = [m'[0..255] | v'[0..255]].  64 rows x 256 cols per block, 8 waves.
// ---------------------------------------------------------------------------
__global__ __launch_bounds__(512) void dense_kernel(
    const float* __restrict__ mean, const float* __restrict__ var,
    const unsigned short* __restrict__ Wt,
    const float* __restrict__ bm, const float* __restrict__ bv,
    unsigned short* __restrict__ mv, int N)
{
    __shared__ unsigned short Asm[64][40];
    __shared__ unsigned short Asv[64][40];
    __shared__ unsigned short Bsm[256][40];
    __shared__ unsigned short Bsv[256][40];

    const int tid  = threadIdx.x;
    const int row0 = blockIdx.x * 64;
    const int lane = tid & 63;
    const int w    = tid >> 6;
    const int wr   = w >> 2;          // 0..1 : 32-row half
    const int wc   = w & 3;           // 0..3 : 64-col slice
    const int lr   = lane & 15;
    const int lk   = lane >> 4;

    f32x4 accm[2][4], accv[2][4];
    #pragma unroll
    for (int i = 0; i < 2; ++i)
        #pragma unroll
        for (int j = 0; j < 4; ++j) { accm[i][j] = (f32x4)0.f; accv[i][j] = (f32x4)0.f; }

    // A-staging: 512 threads cover 64 rows x 32 k (4 floats each)
    const int srow = tid >> 3;
    const int skq  = (tid & 7) * 4;
    int sgrow = row0 + srow; if (sgrow >= N) sgrow = N - 1;

    const unsigned short* WtV = Wt + (size_t)8 * 256 * 32;

    for (int ks = 0; ks < F / KSTEP; ++ks) {
        const int k0 = ks * KSTEP;
        // stage A (f32 -> bf16)
        {
            const float4 am = *(const float4*)&mean[(size_t)sgrow * F + k0 + skq];
            const float4 av = *(const float4*)&var [(size_t)sgrow * F + k0 + skq];
            ushort4 um = { f2b(am.x), f2b(am.y), f2b(am.z), f2b(am.w) };
            ushort4 uv = { f2b(av.x), f2b(av.y), f2b(av.z), f2b(av.w) };
            *(ushort4*)&Asm[srow][skq] = um;
            *(ushort4*)&Asv[srow][skq] = uv;
        }
        // stage B: flat coalesced copy of the pre-tiled 16KB slice (x2)
        {
            const unsigned short* sm = Wt  + (size_t)(ks * 256) * 32;
            const unsigned short* sv = WtV + (size_t)(ks * 256) * 32;
            #pragma unroll
            for (int h = 0; h < 2; ++h) {
                int c = tid + h * 512;       // 16B chunk id, 0..1023
                int n = c >> 2, q = c & 3;
                *(ushort8*)&Bsm[n][q * 8] = *(const ushort8*)(sm + (size_t)n * 32 + q * 8);
                *(ushort8*)&Bsv[n][q * 8] = *(const ushort8*)(sv + (size_t)n * 32 + q * 8);
            }
        }
        __syncthreads();

        bhalf8 am0 = *(const bhalf8*)&Asm[wr*32 +  0 + lr][lk*8];
        bhalf8 am1 = *(const bhalf8*)&Asm[wr*32 + 16 + lr][lk*8];
        bhalf8 av0 = *(const bhalf8*)&Asv[wr*32 +  0 + lr][lk*8];
        bhalf8 av1 = *(const bhalf8*)&Asv[wr*32 + 16 + lr][lk*8];
        #pragma unroll
        for (int ct = 0; ct < 4; ++ct) {
            bhalf8 bmf = *(const bhalf8*)&Bsm[wc*64 + ct*16 + lr][lk*8];
            bhalf8 bvf = *(const bhalf8*)&Bsv[wc*64 + ct*16 + lr][lk*8];
            accm[0][ct] = __builtin_amdgcn_mfma_f32_16x16x32_bf16(am0, bmf, accm[0][ct], 0, 0, 0);
            accm[1][ct] = __builtin_amdgcn_mfma_f32_16x16x32_bf16(am1, bmf, accm[1][ct], 0, 0, 0);
            accv[0][ct] = __builtin_amdgcn_mfma_f32_16x16x32_bf16(av0, bvf, accv[0][ct], 0, 0, 0);
            accv[1][ct] = __builtin_amdgcn_mfma_f32_16x16x32_bf16(av1, bvf, accv[1][ct], 0, 0, 0);
        }
        __syncthreads();
    }

    // epilogue: bias + elu/relu + attention, store bf16 interleaved
    #pragma unroll
    for (int rt = 0; rt < 2; ++rt) {
        #pragma unroll
        for (int ct = 0; ct < 4; ++ct) {
            const int col = wc*64 + ct*16 + lr;
            const float bmc = bm[col], bvc = bv[col];
            #pragma unroll
            for (int q = 0; q < 4; ++q) {
                int grow = row0 + wr*32 + rt*16 + lk*4 + q;
                if (grow < N) {
                    float mp = accm[rt][ct][q] + bmc;
                    float vp = accv[rt][ct][q] + bvc;
                    float me = mp > 0.f ? mp : (__expf(mp) - 1.f);   // elu
                    float vr = vp > 0.f ? vp : 0.f;                  // relu
                    float att = __expf(-vr);
                    mv[(size_t)grow * 512 + col]       = f2b(me * att);
                    mv[(size_t)grow * 512 + 256 + col] = f2b(vr * att * att);
                }
            }
        }
    }
}

// ---------------------------------------------------------------------------
// CSR build
// ---------------------------------------------------------------------------
__global__ void hist_kernel(const int* __restrict__ row, int E, int* __restrict__ count) {
    int i = blockIdx.x * blockDim.x + threadIdx.x;
    if (i < E) atomicAdd(&count[row[i]], 1);
}

__global__ __launch_bounds__(256) void scan1_kernel(const int* __restrict__ count, int N,
                                                    int* __restrict__ offs, int* __restrict__ bsums)
{
    __shared__ int sd[256];
    int t  = threadIdx.x;
    int gi = blockIdx.x * 1024 + t * 4;
    int c[4];
    #pragma unroll
    for (int q = 0; q < 4; ++q) c[q] = (gi + q < N) ? count[gi + q] : 0;
    int s = c[0] + c[1] + c[2] + c[3];
    sd[t] = s; __syncthreads();
    int acc = s;
    for (int off = 1; off < 256; off <<= 1) {
        int u = (t >= off) ? sd[t - off] : 0;
        __syncthreads();
        acc += u; sd[t] = acc;
        __syncthreads();
    }
    int run = acc - s;
    #pragma unroll
    for (int q = 0; q < 4; ++q) { if (gi + q < N) offs[gi + q] = run; run += c[q]; }
    if (t == 255) bsums[blockIdx.x] = acc;
}

__global__ __launch_bounds__(128) void scan2_kernel(int* __restrict__ bsums, int SB,
                                                    int* __restrict__ offs, int N)
{
    __shared__ int sd[128];
    int t = threadIdx.x;
    int v = (t < SB) ? bsums[t] : 0;
    sd[t] = v; __syncthreads();
    int acc = v;
    for (int off = 1; off < 128; off <<= 1) {
        int u = (t >= off) ? sd[t - off] : 0;
        __syncthreads();
        acc += u; sd[t] = acc;
        __syncthreads();
    }
    if (t < SB) bsums[t] = acc - v;
    if (t == 127) offs[N] = sd[127];
}

__global__ __launch_bounds__(256) void scan3_kernel(int* __restrict__ offs, int N,
                                                    const int* __restrict__ bsums)
{
    int b  = bsums[blockIdx.x];
    int gi = blockIdx.x * 1024 + threadIdx.x * 4;
    #pragma unroll
    for (int q = 0; q < 4; ++q) if (gi + q < N) offs[gi + q] += b;
}

__global__ void fill_kernel(const int* __restrict__ row, const int* __restrict__ col,
                            const float* __restrict__ a0, const float* __restrict__ a1,
                            int E, int* __restrict__ cursor,
                            int* __restrict__ ccol, float2* __restrict__ cvv)
{
    int i = blockIdx.x * blockDim.x + threadIdx.x;
    if (i < E) {
        int r   = row[i];
        int pos = atomicAdd(&cursor[r], 1);
        ccol[pos] = col[i];
        float2 vv = { a0[i], a1[i] };
        cvv[pos]  = vv;
    }
}

// ---------------------------------------------------------------------------
// Fused SpMM: 1 wave per node, one 1KB gather per edge (lanes 0-31: m,
// lanes 32-63: v), unrolled x4 for 4 gathers in flight.
// ---------------------------------------------------------------------------
__global__ __launch_bounds__(256) void spmm_kernel(
    const int* __restrict__ offs, const int* __restrict__ ccol,
    const float2* __restrict__ cvv,
    const unsigned short* __restrict__ mv,
    float* __restrict__ out, int N)
{
    int w    = threadIdx.x >> 6;
    int lane = threadIdx.x & 63;
    int node = blockIdx.x * 4 + w;
    if (node >= N) return;
    int s = offs[node], e = offs[node + 1];

    const bool isv = lane >= 32;
    const int  fb  = (lane & 31) * 8;                    // feature base
    const unsigned short* base = mv + (isv ? 256 : 0) + fb;

    float acc[8];
    #pragma unroll
    for (int q = 0; q < 8; ++q) acc[q] = 0.f;

    int j = s;
    for (; j + 3 < e; j += 4) {
        int c0 = ccol[j], c1 = ccol[j+1], c2 = ccol[j+2], c3 = ccol[j+3];
        float2 w0 = cvv[j], w1 = cvv[j+1], w2 = cvv[j+2], w3 = cvv[j+3];
        ushort8 p0 = *(const ushort8*)(base + (size_t)c0 * 512);
        ushort8 p1 = *(const ushort8*)(base + (size_t)c1 * 512);
        ushort8 p2 = *(const ushort8*)(base + (size_t)c2 * 512);
        ushort8 p3 = *(const ushort8*)(base + (size_t)c3 * 512);
        float a0 = isv ? w0.y : w0.x;
        float a1 = isv ? w1.y : w1.x;
        float a2 = isv ? w2.y : w2.x;
        float a3 = isv ? w3.y : w3.x;
        #pragma unroll
        for (int q = 0; q < 8; ++q) acc[q] += a0 * b2f(p0[q]);
        #pragma unroll
        for (int q = 0; q < 8; ++q) acc[q] += a1 * b2f(p1[q]);
        #pragma unroll
        for (int q = 0; q < 8; ++q) acc[q] += a2 * b2f(p2[q]);
        #pragma unroll
        for (int q = 0; q < 8; ++q) acc[q] += a3 * b2f(p3[q]);
    }
    for (; j < e; ++j) {
        int c = ccol[j];
        float2 wv = cvv[j];
        ushort8 p = *(const ushort8*)(base + (size_t)c * 512);
        float a = isv ? wv.y : wv.x;
        #pragma unroll
        for (int q = 0; q < 8; ++q) acc[q] += a * b2f(p[q]);
    }

    float* obase = out + (isv ? (size_t)N * F : 0) + (size_t)node * F + fb;
    float4 o0 = { acc[0], acc[1], acc[2], acc[3] };
    float4 o1 = { acc[4], acc[5], acc[6], acc[7] };
    *(float4*)obase       = o0;
    *(float4*)(obase + 4) = o1;
}

// ---------------------------------------------------------------------------
extern "C" void kernel_launch(void* const* d_in, const int* in_sizes, int n_in,
                              void* d_out, int out_size, void* d_ws, size_t ws_size,
                              hipStream_t stream)
{
    const float* mean = (const float*)d_in[0];
    const float* var  = (const float*)d_in[1];
    const float* Wm   = (const float*)d_in[2];
    const float* bm   = (const float*)d_in[3];
    const float* Wv   = (const float*)d_in[4];
    const float* bv   = (const float*)d_in[5];
    const int*   erow = (const int*)d_in[6];
    const int*   ecol = (const int*)d_in[7];
    const float* a0   = (const float*)d_in[8];
    const float* a1   = (const float*)d_in[9];

    const int N = in_sizes[0] / F;     // 100000
    const int E = in_sizes[6];         // 3200000

    uintptr_t p = (uintptr_t)d_ws;
    auto take = [&](size_t bytes) {
        uintptr_t r = (p + 255) & ~(uintptr_t)255;
        p = r + bytes;
        return (void*)r;
    };
    unsigned short* mv   = (unsigned short*)take((size_t)N * 512 * 2);
    int*            ccol = (int*)take((size_t)E * 4);
    float2*         cvv  = (float2*)take((size_t)E * 8);
    int*            count  = (int*)take((size_t)N * 4);
    int*            offs   = (int*)take((size_t)(N + 1) * 4);
    int*            cursor = (int*)take((size_t)N * 4);
    int*            bsums  = (int*)take(1024 * 4);
    unsigned short* Wt     = (unsigned short*)take((size_t)2 * 8 * 256 * 32 * 2);

    const int SB = (N + 1023) / 1024;

    hipMemsetAsync(count, 0, (size_t)N * 4, stream);

    wprep_kernel<<<16, 256, 0, stream>>>(Wm, Wv, Wt);
    dense_kernel<<<(N + 63) / 64, 512, 0, stream>>>(mean, var, Wt, bm, bv, mv, N);

    hist_kernel<<<(E + 255) / 256, 256, 0, stream>>>(erow, E, count);
    scan1_kernel<<<SB, 256, 0, stream>>>(count, N, offs, bsums);
    scan2_kernel<<<1, 128, 0, stream>>>(bsums, SB, offs, N);
    scan3_kernel<<<SB, 256, 0, stream>>>(offs, N, bsums);
    hipMemcpyAsync(cursor, offs, (size_t)N * 4, hipMemcpyDeviceToDevice, stream);
    fill_kernel<<<(E + 255) / 256, 256, 0, stream>>>(erow, ecol, a0, a1, E, cursor, ccol, cvv);

    spmm_kernel<<<(N + 3) / 4, 256, 0, stream>>>(offs, ccol, cvv, mv, (float*)d_out, N);
}